// Round 6
// baseline (270.038 us; speedup 1.0000x reference)
//
#include <hip/hip_runtime.h>
#include <hip/hip_bf16.h>
#include <math.h>

typedef unsigned short u16;
typedef __attribute__((ext_vector_type(8))) __bf16 bf16x8;
typedef __attribute__((ext_vector_type(4))) float f32x4;

__device__ __forceinline__ float bf2f(u16 u) {
  union { unsigned int i; float f; } v; v.i = ((unsigned int)u) << 16; return v.f;
}
__device__ __forceinline__ u16 f2bf(float f) {
  union { unsigned int i; float f; } v; v.f = f;
  unsigned int r = v.i + 0x7fffu + ((v.i >> 16) & 1u);
  return (u16)(r >> 16);
}

// async global->LDS, 16B per lane. LDS dest = wave-uniform base + lane*16.
__device__ __forceinline__ void gload16(const u16* g, u16* l) {
  __builtin_amdgcn_global_load_lds((const __attribute__((address_space(1))) unsigned int*)g,
                                   (__attribute__((address_space(3))) unsigned int*)l, 16, 0, 0);
}

// ---------------- K1: LayerNorm msa -> x (bf16). one wave per row ----------------
__global__ __launch_bounds__(256) void k_ln(
    const float* __restrict__ msa, const float* __restrict__ lnw,
    const float* __restrict__ lnb, u16* __restrict__ xbf) {
  const int row  = blockIdx.x * 4 + (threadIdx.x >> 6);
  const int lane = threadIdx.x & 63;
  const float4 v = ((const float4*)(msa + (size_t)row * 256))[lane];
  float s = v.x + v.y + v.z + v.w;
  #pragma unroll
  for (int m = 1; m < 64; m <<= 1) s += __shfl_xor(s, m, 64);
  const float mu = s * (1.0f / 256.0f);
  const float d0 = v.x - mu, d1 = v.y - mu, d2 = v.z - mu, d3 = v.w - mu;
  float q = d0*d0 + d1*d1 + d2*d2 + d3*d3;
  #pragma unroll
  for (int m = 1; m < 64; m <<= 1) q += __shfl_xor(q, m, 64);
  const float rstd = rsqrtf(q * (1.0f / 256.0f) + 1e-5f);
  const int c = lane * 4;
  ushort4 o;
  o.x = f2bf(d0 * rstd * lnw[c+0] + lnb[c+0]);
  o.y = f2bf(d1 * rstd * lnw[c+1] + lnb[c+1]);
  o.z = f2bf(d2 * rstd * lnw[c+2] + lnb[c+2]);
  o.w = f2bf(d3 * rstd * lnw[c+3] + lnb[c+3]);
  ((ushort4*)(xbf + (size_t)row * 256))[lane] = o;
}

// ---------------- K2a: pack proj weights (kw||wl||wr) -> Wbf[320][256] bf16 ----------------
__global__ __launch_bounds__(256) void k_wpackW(
    const float* __restrict__ kw, const float* __restrict__ wl,
    const float* __restrict__ wr, u16* __restrict__ Wbf) {
  const int row = blockIdx.x;
  const int t = threadIdx.x;
  const float* src = (row < 256) ? kw + (size_t)row * 256
                   : (row < 288) ? wl + (size_t)(row - 256) * 256
                                 : wr + (size_t)(row - 288) * 256;
  Wbf[(size_t)row * 256 + t] = f2bf(src[t]);
}

// ---------------- K2b: proj GEMM (MFMA) x(65536x256) @ Wbf.T(256x320) ----------------
__global__ __launch_bounds__(256, 2) void k_proj_mfma(
    const u16* __restrict__ xbf, const u16* __restrict__ Wbf,
    u16* __restrict__ kproj, float* __restrict__ araw, float* __restrict__ braw) {
  __shared__ __align__(16) u16 lds[6144];
  const int t = threadIdx.x, l = t & 63, wid = t >> 6;
  const int wm = wid >> 1, wn = wid & 1;
  const int mb = blockIdx.x * 128;
  const int nb = blockIdx.y * 64;
  u16* As = lds;
  u16* Bs = lds + 4096;
  f32x4 acc[4][2] = {};
  const int lrow = l >> 2, lslot = l & 3;
  const int ksl = ((l >> 4) ^ ((l >> 1) & 3)) * 8;
  for (int kb = 0; kb < 256; kb += 32) {
    #pragma unroll
    for (int q = 0; q < 2; ++q) {
      const int op = wid * 2 + q;
      const int row = op * 16 + lrow;
      gload16(xbf + (size_t)(mb + row) * 256 + kb + ((lslot ^ ((row >> 1) & 3)) * 8),
              As + op * 512);
    }
    {
      const int row = wid * 16 + lrow;
      gload16(Wbf + (size_t)(nb + row) * 256 + kb + ((lslot ^ ((row >> 1) & 3)) * 8),
              Bs + wid * 512);
    }
    __syncthreads();
    bf16x8 af[4], bfr[2];
    #pragma unroll
    for (int mt = 0; mt < 4; ++mt)
      af[mt] = *(const bf16x8*)&As[(wm * 64 + mt * 16 + (l & 15)) * 32 + ksl];
    #pragma unroll
    for (int nt = 0; nt < 2; ++nt)
      bfr[nt] = *(const bf16x8*)&Bs[(wn * 32 + nt * 16 + (l & 15)) * 32 + ksl];
    #pragma unroll
    for (int mt = 0; mt < 4; ++mt)
      #pragma unroll
      for (int nt = 0; nt < 2; ++nt)
        acc[mt][nt] = __builtin_amdgcn_mfma_f32_16x16x32_bf16(af[mt], bfr[nt], acc[mt][nt], 0, 0, 0);
    __syncthreads();
  }
  const int cl = l & 15, rbase = (l >> 4) * 4;
  if (nb < 256) {
    #pragma unroll
    for (int mt = 0; mt < 4; ++mt)
      #pragma unroll
      for (int nt = 0; nt < 2; ++nt) {
        const int col = nb + wn * 32 + nt * 16 + cl;
        #pragma unroll
        for (int r = 0; r < 4; ++r) {
          const int row = mb + wm * 64 + mt * 16 + rbase + r;
          kproj[(size_t)row * 256 + col] = f2bf(acc[mt][nt][r]);
        }
      }
  } else {
    #pragma unroll
    for (int mt = 0; mt < 4; ++mt)
      #pragma unroll
      for (int nt = 0; nt < 2; ++nt) {
        const int c = wn * 32 + nt * 16 + cl;
        float* dst = (c < 32) ? araw : braw;
        const int cc = c & 31;
        #pragma unroll
        for (int r = 0; r < 4; ++r) {
          const int row = mb + wm * 64 + mt * 16 + rbase + r;
          dst[(size_t)row * 32 + cc] = acc[mt][nt][r];
        }
      }
  }
}

// ---------------- K3: q = LN(x[0] @ q_w.T per 128-half) + per-n prep for k_sw ----------------
__global__ __launch_bounds__(256) void k_q(
    const u16* __restrict__ xbf, const float* __restrict__ qw,
    const float* __restrict__ qnw, const float* __restrict__ qnb,
    const float* __restrict__ knw, const float* __restrict__ knb,
    float* __restrict__ wqws, float* __restrict__ Swqws, float* __restrict__ bqws) {
  __shared__ float xrow[256];
  __shared__ float qbuf[256];
  __shared__ float rbuf[256];
  const int t = threadIdx.x;
  const int n = blockIdx.x;
  xrow[t] = bf2f(xbf[(size_t)n * 256 + t]);
  __syncthreads();
  float acc = 0.f;
  const float* w = qw + (size_t)t * 256;
  for (int d = 0; d < 256; ++d) acc += xrow[d] * w[d];
  qbuf[t] = acc;
  __syncthreads();
  const int half = t >> 7, idx = t & 127;
  const float* hb = &qbuf[half * 128];
  float s = 0.f;
  for (int d = 0; d < 128; ++d) s += hb[d];
  const float mu = s * (1.0f / 128.0f);
  float vv = 0.f;
  for (int d = 0; d < 128; ++d) { float dd = hb[d] - mu; vv += dd * dd; }
  const float rstd = rsqrtf(vv * (1.0f / 128.0f) + 1e-5f);
  const float qv = (acc - mu) * rstd * qnw[idx] + qnb[idx];
  const float wqv = knw[idx] * qv;
  const float bqv = knb[idx] * qv;
  wqws[(size_t)(half * 256 + n) * 128 + idx] = wqv;
  rbuf[t] = wqv; __syncthreads();
  for (int st = 64; st > 0; st >>= 1) { if ((t & 127) < st) rbuf[t] += rbuf[t + st]; __syncthreads(); }
  if (t == 0)   Swqws[n]       = rbuf[0];
  if (t == 128) Swqws[256 + n] = rbuf[128];
  __syncthreads();
  rbuf[t] = bqv; __syncthreads();
  for (int st = 64; st > 0; st >>= 1) { if ((t & 127) < st) rbuf[t] += rbuf[t + st]; __syncthreads(); }
  if (t == 0)   bqws[n]       = rbuf[0];
  if (t == 128) bqws[256 + n] = rbuf[128];
}

// ---------------- K4: sw partials via moment-expanded LN dot ----------------
__global__ __launch_bounds__(256) void k_sw2(
    const u16* __restrict__ kproj, const float* __restrict__ wqws,
    const float* __restrict__ Swqws, const float* __restrict__ bqws,
    float* __restrict__ swpart) {
  const int s = blockIdx.x, g = blockIdx.y;
  const int t = threadIdx.x, w = t >> 6, l = t & 63;
  const int h = l >> 5, j = l & 31;
  __shared__ float part[2][4];
  float accv = 0.f;
  #pragma unroll
  for (int i = 0; i < 4; ++i) {
    const int n = g * 16 + w * 4 + i;
    const u16* kr = kproj + ((size_t)s * 256 + n) * 256 + h * 128 + j * 4;
    const ushort4 k4 = *(const ushort4*)kr;
    const float4 wq4 = *(const float4*)(wqws + ((size_t)h * 256 + n) * 128 + j * 4);
    const float k0 = bf2f(k4.x), k1 = bf2f(k4.y), k2 = bf2f(k4.z), k3 = bf2f(k4.w);
    float sk  = k0 + k1 + k2 + k3;
    float sk2 = k0*k0 + k1*k1 + k2*k2 + k3*k3;
    float skw = k0*wq4.x + k1*wq4.y + k2*wq4.z + k3*wq4.w;
    #pragma unroll
    for (int m = 1; m < 32; m <<= 1) {
      sk  += __shfl_xor(sk,  m, 64);
      sk2 += __shfl_xor(sk2, m, 64);
      skw += __shfl_xor(skw, m, 64);
    }
    const float mu = sk * (1.0f / 128.0f);
    const float var = sk2 * (1.0f / 128.0f) - mu * mu;
    const float rstd = rsqrtf(var + 1e-5f);
    accv += rstd * (skw - mu * Swqws[h * 256 + n]) + bqws[h * 256 + n];
  }
  if (j == 0) part[h][w] = accv;
  __syncthreads();
  if (t < 2) {
    const float r = part[t][0] + part[t][1] + part[t][2] + part[t][3];
    swpart[((size_t)t * 256 + s) * 16 + g] = r;
  }
}

// ---------------- K5: lambda + partial-reduce + softmax -> seq_weights (out) + sqrt scale ----------------
__global__ __launch_bounds__(256) void k_softmax(
    const float* __restrict__ swpart, const float* __restrict__ lq1,
    const float* __restrict__ lk1, const float* __restrict__ lq2,
    const float* __restrict__ lk2, float* __restrict__ seqw_out,
    float* __restrict__ scl) {
  __shared__ float rbuf[256];
  const int t = threadIdx.x;
  const float p1 = (t < 128) ? lq1[t] * lk1[t] : 0.f;
  const float p2 = (t < 128) ? lq2[t] * lk2[t] : 0.f;
  rbuf[t] = p1; __syncthreads();
  for (int st = 128; st > 0; st >>= 1) { if (t < st) rbuf[t] += rbuf[t+st]; __syncthreads(); }
  const float s1 = rbuf[0]; __syncthreads();
  rbuf[t] = p2; __syncthreads();
  for (int st = 128; st > 0; st >>= 1) { if (t < st) rbuf[t] += rbuf[t+st]; __syncthreads(); }
  const float s2 = rbuf[0]; __syncthreads();
  const float lam = expf(s1) - expf(s2) + 0.2f;
  const float sc = (1.0f / sqrtf(128.0f)) / (256.0f + 1e-8f);
  float sw0 = 0.f, sw1 = 0.f;
  {
    const float* p0 = swpart + (size_t)t * 16;
    const float* p1p = swpart + (size_t)(256 + t) * 16;
    #pragma unroll
    for (int kk = 0; kk < 4; ++kk) {
      const float4 a = *(const float4*)(p0 + kk * 4);
      const float4 b = *(const float4*)(p1p + kk * 4);
      sw0 += a.x + a.y + a.z + a.w;
      sw1 += b.x + b.y + b.z + b.w;
    }
    sw0 *= sc; sw1 *= sc;
  }
  const float swv = sw0 - lam * sw1;
  rbuf[t] = swv; __syncthreads();
  for (int st = 128; st > 0; st >>= 1) { if (t < st) rbuf[t] = fmaxf(rbuf[t], rbuf[t+st]); __syncthreads(); }
  const float mx = rbuf[0]; __syncthreads();
  const float e = expf(swv - mx);
  rbuf[t] = e; __syncthreads();
  for (int st = 128; st > 0; st >>= 1) { if (t < st) rbuf[t] += rbuf[t+st]; __syncthreads(); }
  const float Z = rbuf[0];
  const float wgt = e / Z;
  seqw_out[t] = wgt;
  scl[t] = sqrtf(wgt + 1e-8f);
}

// ---------------- K6: transpose+scale -> AscT/BscT bf16 [8192 rows ic][256 s] ----------------
__global__ __launch_bounds__(256) void k_scaleT(
    const float* __restrict__ araw, const float* __restrict__ braw,
    const float* __restrict__ scl, u16* __restrict__ AscT, u16* __restrict__ BscT) {
  __shared__ float tileT[32][257];
  const int t = threadIdx.x;
  const int n = blockIdx.x;
  for (int pass = 0; pass < 2; ++pass) {
    const float* src = pass ? braw : araw;
    u16* dst = pass ? BscT : AscT;
    if (pass) __syncthreads();
    {
      const int sl = t >> 5, c = t & 31;
      for (int it = 0; it < 32; ++it) {
        const int s = it * 8 + sl;
        tileT[c][s] = src[((size_t)s * 256 + n) * 32 + c] * scl[s];
      }
    }
    __syncthreads();
    {
      const int c = t >> 3, s0 = (t & 7) * 32;
      u16* drow = dst + (size_t)(n * 32 + c) * 256 + s0;
      #pragma unroll
      for (int kk = 0; kk < 4; ++kk) {
        ushort4 p0, p1;
        p0.x = f2bf(tileT[c][s0 + kk*8 + 0]); p0.y = f2bf(tileT[c][s0 + kk*8 + 1]);
        p0.z = f2bf(tileT[c][s0 + kk*8 + 2]); p0.w = f2bf(tileT[c][s0 + kk*8 + 3]);
        p1.x = f2bf(tileT[c][s0 + kk*8 + 4]); p1.y = f2bf(tileT[c][s0 + kk*8 + 5]);
        p1.z = f2bf(tileT[c][s0 + kk*8 + 6]); p1.w = f2bf(tileT[c][s0 + kk*8 + 7]);
        *(ushort4*)(drow + kk*8 + 0) = p0;
        *(ushort4*)(drow + kk*8 + 4) = p1;
      }
    }
  }
}

// ---------------- K6b: wp f32 -> bf16 ----------------
__global__ __launch_bounds__(256) void k_wpack(const float* __restrict__ wp, u16* __restrict__ wpbf) {
  const size_t i = ((size_t)blockIdx.x * 256 + threadIdx.x) * 4;
  const float4 v = *(const float4*)&wp[i];
  ushort4 o; o.x = f2bf(v.x); o.y = f2bf(v.y); o.z = f2bf(v.z); o.w = f2bf(v.w);
  *(ushort4*)&wpbf[i] = o;
}

// ---------------- K7: FUSED outer+pair+SiLU ----------------
// block: ic-tile 128 (i-blk of 4) x je-tile 256 (j-blk of 8). grid (64, 32).
// phase 1: outer GEMM 128x256 K=256 (proven k_outer loop)
// repack:  acc -> P[32 ij][1024 ce] bf16 in LDS, XOR swizzle (ij&7)<<4
// phase 2: pair GEMM M=32 x N=256 p, K=1024 ce; wp staged per-32ce, double-buffered
// epilogue: bias + SiLU -> out (f32), no outer materialization in HBM.
// dynamic LDS 96KB: P @0 (64KB), stage @65536 (32KB; ph1: As 8KB + Bs 16KB; ph2: 2x16KB dbuf)
__global__ __launch_bounds__(256, 1) void k_op(
    const u16* __restrict__ AscT, const u16* __restrict__ BscT,
    const u16* __restrict__ wpbf, const float* __restrict__ bp,
    float* __restrict__ out) {
  extern __shared__ char lds_dyn[];
  char* Pb = lds_dyn;                        // 64KB: P[32][1024] bf16, row stride 2048B
  u16* stage = (u16*)(lds_dyn + 65536);      // 32KB
  const int t = threadIdx.x, l = t & 63, wid = t >> 6;
  const int wm = wid >> 1, wn = wid & 1;
  const int ib = blockIdx.x, jb = blockIdx.y;
  const int lrow = l >> 2, lslot = l & 3;
  const int ksl = ((l >> 4) ^ ((l >> 1) & 3)) * 8;

  // ---- phase 1: outer tile 128 ic x 256 je, K=256 ----
  u16* As = stage;               // 128x32 = 4096 u16
  u16* Bs = stage + 4096;        // 256x32 = 8192 u16
  f32x4 acc[4][8] = {};
  for (int kb = 0; kb < 256; kb += 32) {
    #pragma unroll
    for (int q = 0; q < 2; ++q) {
      const int op = wid * 2 + q;
      const int row = op * 16 + lrow;
      gload16(AscT + (size_t)(ib * 128 + row) * 256 + kb + ((lslot ^ ((row >> 1) & 3)) * 8),
              As + op * 512);
    }
    #pragma unroll
    for (int q = 0; q < 4; ++q) {
      const int op = wid * 4 + q;
      const int row = op * 16 + lrow;
      gload16(BscT + (size_t)(jb * 256 + row) * 256 + kb + ((lslot ^ ((row >> 1) & 3)) * 8),
              Bs + op * 512);
    }
    __syncthreads();
    bf16x8 af[4], bfr[8];
    #pragma unroll
    for (int mt = 0; mt < 4; ++mt)
      af[mt] = *(const bf16x8*)&As[(wm * 64 + mt * 16 + (l & 15)) * 32 + ksl];
    #pragma unroll
    for (int nt = 0; nt < 8; ++nt)
      bfr[nt] = *(const bf16x8*)&Bs[(wn * 128 + nt * 16 + (l & 15)) * 32 + ksl];
    #pragma unroll
    for (int mt = 0; mt < 4; ++mt)
      #pragma unroll
      for (int nt = 0; nt < 8; ++nt)
        acc[mt][nt] = __builtin_amdgcn_mfma_f32_16x16x32_bf16(af[mt], bfr[nt], acc[mt][nt], 0, 0, 0);
    __syncthreads();
  }

  // issue phase-2 prologue stage (kb=0) early: overlaps with repack.
  u16* buf0 = stage;
  u16* buf1 = stage + 8192;
  #pragma unroll
  for (int q = 0; q < 4; ++q) {
    const int rw = wid * 64 + q * 16 + lrow;
    gload16(wpbf + (size_t)rw * 1024 + ((lslot ^ ((rw >> 1) & 3)) * 8), buf0 + (wid * 4 + q) * 512);
  }

  // ---- repack: acc -> P[ij][ce] bf16, swizzled ----
  {
    #pragma unroll
    for (int mt = 0; mt < 4; ++mt) {
      #pragma unroll
      for (int nt = 0; nt < 8; ++nt) {
        const int ij = (wm * 2 + (mt >> 1)) * 8 + wn * 4 + (nt >> 1);
        const int e  = (nt & 1) * 16 + (l & 15);
        #pragma unroll
        for (int r = 0; r < 4; ++r) {
          const int c = (mt & 1) * 16 + (l >> 4) * 4 + r;
          const int ce = c * 32 + e;
          *(u16*)(Pb + ij * 2048 + ((ce * 2) ^ ((ij & 7) << 4))) = f2bf(acc[mt][nt][r]);
        }
      }
    }
  }
  __syncthreads();   // P complete + buf0 staged (vmcnt drained at barrier)

  // ---- phase 2: pair = P @ wp^T, M=32, N=256, K=1024 ----
  f32x4 pacc[2][4] = {};
  for (int s = 0; s < 32; ++s) {
    const int kb = s * 32;
    u16* cur = (s & 1) ? buf1 : buf0;
    u16* nxt = (s & 1) ? buf0 : buf1;
    if (s + 1 < 32) {
      #pragma unroll
      for (int q = 0; q < 4; ++q) {
        const int rw = wid * 64 + q * 16 + lrow;
        gload16(wpbf + (size_t)rw * 1024 + (kb + 32) + ((lslot ^ ((rw >> 1) & 3)) * 8),
                nxt + (wid * 4 + q) * 512);
      }
    }
    bf16x8 paf[2], bfr[4];
    #pragma unroll
    for (int mf = 0; mf < 2; ++mf) {
      const int row = mf * 16 + (l & 15);
      paf[mf] = *(const bf16x8*)(Pb + row * 2048 + (((kb + (l >> 4) * 8) * 2) ^ ((row & 7) << 4)));
    }
    #pragma unroll
    for (int nt = 0; nt < 4; ++nt)
      bfr[nt] = *(const bf16x8*)&cur[(wid * 64 + nt * 16 + (l & 15)) * 32 + ksl];
    #pragma unroll
    for (int mf = 0; mf < 2; ++mf)
      #pragma unroll
      for (int nt = 0; nt < 4; ++nt)
        pacc[mf][nt] = __builtin_amdgcn_mfma_f32_16x16x32_bf16(paf[mf], bfr[nt], pacc[mf][nt], 0, 0, 0);
    __syncthreads();
  }

  // ---- epilogue: bias, SiLU, store ----
  float* pairS = (float*)Pb;     // [32][260] f32 = 33280 B <= 64KB (P dead)
  {
    float bpv[4];
    #pragma unroll
    for (int nt = 0; nt < 4; ++nt) bpv[nt] = bp[wid * 64 + nt * 16 + (l & 15)];
    #pragma unroll
    for (int mf = 0; mf < 2; ++mf)
      #pragma unroll
      for (int nt = 0; nt < 4; ++nt) {
        const int col = wid * 64 + nt * 16 + (l & 15);
        #pragma unroll
        for (int r = 0; r < 4; ++r) {
          const int row = mf * 16 + (l >> 4) * 4 + r;
          pairS[row * 260 + col] = pacc[mf][nt][r] + bpv[nt];
        }
      }
  }
  __syncthreads();
  {
    const int r32 = t >> 3, h0 = (t & 7) * 16;
    const int i_loc = r32 >> 3, j_loc = r32 & 7;
    float* orow = out + ((size_t)(ib * 4 + i_loc) * 256 + jb * 8 + j_loc) * 128 + h0;
    #pragma unroll
    for (int kk = 0; kk < 4; ++kk) {
      const float4 xh = *(const float4*)&pairS[r32 * 260 + h0 + kk * 4];
      const float4 g  = *(const float4*)&pairS[r32 * 260 + 128 + h0 + kk * 4];
      float4 o;
      o.x = xh.x * g.x / (1.f + __expf(-g.x));
      o.y = xh.y * g.y / (1.f + __expf(-g.y));
      o.z = xh.z * g.z / (1.f + __expf(-g.z));
      o.w = xh.w * g.w / (1.f + __expf(-g.w));
      *(float4*)&orow[kk * 4] = o;
    }
  }
}

extern "C" void kernel_launch(void* const* d_in, const int* in_sizes, int n_in,
                              void* d_out, int out_size, void* d_ws, size_t ws_size,
                              hipStream_t stream) {
  const float* msa = (const float*)d_in[0];
  const float* lnw = (const float*)d_in[4];
  const float* lnb = (const float*)d_in[5];
  const float* qw  = (const float*)d_in[6];
  const float* qnw = (const float*)d_in[7];
  const float* qnb = (const float*)d_in[8];
  const float* knw = (const float*)d_in[9];
  const float* knb = (const float*)d_in[10];
  const float* lq1 = (const float*)d_in[11];
  const float* lk1 = (const float*)d_in[12];
  const float* lq2 = (const float*)d_in[13];
  const float* lk2 = (const float*)d_in[14];
  const float* wl  = (const float*)d_in[15];
  const float* wr  = (const float*)d_in[16];
  const float* wp  = (const float*)d_in[17];
  const float* bp  = (const float*)d_in[18];
  const float* kw  = (const float*)d_in[19];
  float* out = (float*)d_out;

  char* ws = (char*)d_ws;
  u16*   AscT  = (u16*)(ws);                    //  0 .. 4 MB
  u16*   BscT  = (u16*)(ws + 4194304);          //  4 .. 8 MB
  u16*   wpbf  = (u16*)(ws + 8388608);          //  8 .. 8.5 MB
  float* sclws = (float*)(ws + 9177088);
  u16*   Wbf   = (u16*)(ws + 9178112);          // 320x256 bf16
  u16*   xbf   = (u16*)(ws + 9437184);          //  9 .. 42.5 MB
  u16*   kproj = (u16*)(ws + 42991616);         // 42.5 .. 76.5 MB
  float* araw  = (float*)(ws + 76546048);       // 76.5 .. 84.9 MB
  float* braw  = (float*)(ws + 84934656);       // 84.9 .. 93.3 MB
  float* wqws  = (float*)(ws + 93323264);       // [2][256][128] f32
  float* swpart= (float*)(ws + 93585408);       // [2][256][16] f32
  float* Swqws = (float*)(ws + 93618176);
  float* bqws  = (float*)(ws + 93620224);

  k_ln<<<16384, 256, 0, stream>>>(msa, lnw, lnb, xbf);
  k_wpackW<<<320, 256, 0, stream>>>(kw, wl, wr, Wbf);
  k_proj_mfma<<<dim3(512, 5), 256, 0, stream>>>(xbf, Wbf, kproj, araw, braw);
  k_q<<<256, 256, 0, stream>>>(xbf, qw, qnw, qnb, knw, knb, wqws, Swqws, bqws);
  k_sw2<<<dim3(256, 16), 256, 0, stream>>>(kproj, wqws, Swqws, bqws, swpart);
  k_softmax<<<1, 256, 0, stream>>>(swpart, lq1, lk1, lq2, lk2, out + 8388608, sclws);
  k_scaleT<<<256, 256, 0, stream>>>(araw, braw, sclws, AscT, BscT);
  k_wpack<<<256, 256, 0, stream>>>(wp, wpbf);
  k_op<<<dim3(64, 32), 256, 98304, stream>>>(AscT, BscT, wpbf, bp, out);
}

// Round 7
// 252.019 us; speedup vs baseline: 1.0715x; 1.0715x over previous
//
#include <hip/hip_runtime.h>
#include <hip/hip_bf16.h>
#include <math.h>

typedef unsigned short u16;
typedef __attribute__((ext_vector_type(8))) __bf16 bf16x8;
typedef __attribute__((ext_vector_type(4))) float f32x4;

__device__ __forceinline__ float bf2f(u16 u) {
  union { unsigned int i; float f; } v; v.i = ((unsigned int)u) << 16; return v.f;
}
__device__ __forceinline__ u16 f2bf(float f) {
  union { unsigned int i; float f; } v; v.f = f;
  unsigned int r = v.i + 0x7fffu + ((v.i >> 16) & 1u);
  return (u16)(r >> 16);
}

// async global->LDS, 16B per lane. LDS dest = wave-uniform base + lane*16.
__device__ __forceinline__ void gload16(const u16* g, u16* l) {
  __builtin_amdgcn_global_load_lds((const __attribute__((address_space(1))) unsigned int*)g,
                                   (__attribute__((address_space(3))) unsigned int*)l, 16, 0, 0);
}

// ---------------- K1: LayerNorm msa -> x (bf16). one wave per row ----------------
__global__ __launch_bounds__(256) void k_ln(
    const float* __restrict__ msa, const float* __restrict__ lnw,
    const float* __restrict__ lnb, u16* __restrict__ xbf) {
  const int row  = blockIdx.x * 4 + (threadIdx.x >> 6);
  const int lane = threadIdx.x & 63;
  const float4 v = ((const float4*)(msa + (size_t)row * 256))[lane];
  float s = v.x + v.y + v.z + v.w;
  #pragma unroll
  for (int m = 1; m < 64; m <<= 1) s += __shfl_xor(s, m, 64);
  const float mu = s * (1.0f / 256.0f);
  const float d0 = v.x - mu, d1 = v.y - mu, d2 = v.z - mu, d3 = v.w - mu;
  float q = d0*d0 + d1*d1 + d2*d2 + d3*d3;
  #pragma unroll
  for (int m = 1; m < 64; m <<= 1) q += __shfl_xor(q, m, 64);
  const float rstd = rsqrtf(q * (1.0f / 256.0f) + 1e-5f);
  const int c = lane * 4;
  ushort4 o;
  o.x = f2bf(d0 * rstd * lnw[c+0] + lnb[c+0]);
  o.y = f2bf(d1 * rstd * lnw[c+1] + lnb[c+1]);
  o.z = f2bf(d2 * rstd * lnw[c+2] + lnb[c+2]);
  o.w = f2bf(d3 * rstd * lnw[c+3] + lnb[c+3]);
  ((ushort4*)(xbf + (size_t)row * 256))[lane] = o;
}

// ---------------- K2a: pack proj weights (kw||wl||wr) -> Wbf[320][256] bf16 ----------------
__global__ __launch_bounds__(256) void k_wpackW(
    const float* __restrict__ kw, const float* __restrict__ wl,
    const float* __restrict__ wr, u16* __restrict__ Wbf) {
  const int row = blockIdx.x;
  const int t = threadIdx.x;
  const float* src = (row < 256) ? kw + (size_t)row * 256
                   : (row < 288) ? wl + (size_t)(row - 256) * 256
                                 : wr + (size_t)(row - 288) * 256;
  Wbf[(size_t)row * 256 + t] = f2bf(src[t]);
}

// ---------------- K2b: proj GEMM (MFMA) x(65536x256) @ Wbf.T(256x320) ----------------
__global__ __launch_bounds__(256, 2) void k_proj_mfma(
    const u16* __restrict__ xbf, const u16* __restrict__ Wbf,
    u16* __restrict__ kproj, float* __restrict__ araw, float* __restrict__ braw) {
  __shared__ __align__(16) u16 lds[6144];
  const int t = threadIdx.x, l = t & 63, wid = t >> 6;
  const int wm = wid >> 1, wn = wid & 1;
  const int mb = blockIdx.x * 128;
  const int nb = blockIdx.y * 64;
  u16* As = lds;
  u16* Bs = lds + 4096;
  f32x4 acc[4][2] = {};
  const int lrow = l >> 2, lslot = l & 3;
  const int ksl = ((l >> 4) ^ ((l >> 1) & 3)) * 8;
  for (int kb = 0; kb < 256; kb += 32) {
    #pragma unroll
    for (int q = 0; q < 2; ++q) {
      const int op = wid * 2 + q;
      const int row = op * 16 + lrow;
      gload16(xbf + (size_t)(mb + row) * 256 + kb + ((lslot ^ ((row >> 1) & 3)) * 8),
              As + op * 512);
    }
    {
      const int row = wid * 16 + lrow;
      gload16(Wbf + (size_t)(nb + row) * 256 + kb + ((lslot ^ ((row >> 1) & 3)) * 8),
              Bs + wid * 512);
    }
    __syncthreads();
    bf16x8 af[4], bfr[2];
    #pragma unroll
    for (int mt = 0; mt < 4; ++mt)
      af[mt] = *(const bf16x8*)&As[(wm * 64 + mt * 16 + (l & 15)) * 32 + ksl];
    #pragma unroll
    for (int nt = 0; nt < 2; ++nt)
      bfr[nt] = *(const bf16x8*)&Bs[(wn * 32 + nt * 16 + (l & 15)) * 32 + ksl];
    #pragma unroll
    for (int mt = 0; mt < 4; ++mt)
      #pragma unroll
      for (int nt = 0; nt < 2; ++nt)
        acc[mt][nt] = __builtin_amdgcn_mfma_f32_16x16x32_bf16(af[mt], bfr[nt], acc[mt][nt], 0, 0, 0);
    __syncthreads();
  }
  const int cl = l & 15, rbase = (l >> 4) * 4;
  if (nb < 256) {
    #pragma unroll
    for (int mt = 0; mt < 4; ++mt)
      #pragma unroll
      for (int nt = 0; nt < 2; ++nt) {
        const int col = nb + wn * 32 + nt * 16 + cl;
        #pragma unroll
        for (int r = 0; r < 4; ++r) {
          const int row = mb + wm * 64 + mt * 16 + rbase + r;
          kproj[(size_t)row * 256 + col] = f2bf(acc[mt][nt][r]);
        }
      }
  } else {
    #pragma unroll
    for (int mt = 0; mt < 4; ++mt)
      #pragma unroll
      for (int nt = 0; nt < 2; ++nt) {
        const int c = wn * 32 + nt * 16 + cl;
        float* dst = (c < 32) ? araw : braw;
        const int cc = c & 31;
        #pragma unroll
        for (int r = 0; r < 4; ++r) {
          const int row = mb + wm * 64 + mt * 16 + rbase + r;
          dst[(size_t)row * 32 + cc] = acc[mt][nt][r];
        }
      }
  }
}

// ---------------- K3: q = LN(x[0] @ q_w.T per 128-half) + per-n prep for k_sw ----------------
__global__ __launch_bounds__(256) void k_q(
    const u16* __restrict__ xbf, const float* __restrict__ qw,
    const float* __restrict__ qnw, const float* __restrict__ qnb,
    const float* __restrict__ knw, const float* __restrict__ knb,
    float* __restrict__ wqws, float* __restrict__ Swqws, float* __restrict__ bqws) {
  __shared__ float xrow[256];
  __shared__ float qbuf[256];
  __shared__ float rbuf[256];
  const int t = threadIdx.x;
  const int n = blockIdx.x;
  xrow[t] = bf2f(xbf[(size_t)n * 256 + t]);
  __syncthreads();
  float acc = 0.f;
  const float* w = qw + (size_t)t * 256;
  for (int d = 0; d < 256; ++d) acc += xrow[d] * w[d];
  qbuf[t] = acc;
  __syncthreads();
  const int half = t >> 7, idx = t & 127;
  const float* hb = &qbuf[half * 128];
  float s = 0.f;
  for (int d = 0; d < 128; ++d) s += hb[d];
  const float mu = s * (1.0f / 128.0f);
  float vv = 0.f;
  for (int d = 0; d < 128; ++d) { float dd = hb[d] - mu; vv += dd * dd; }
  const float rstd = rsqrtf(vv * (1.0f / 128.0f) + 1e-5f);
  const float qv = (acc - mu) * rstd * qnw[idx] + qnb[idx];
  const float wqv = knw[idx] * qv;
  const float bqv = knb[idx] * qv;
  wqws[(size_t)(half * 256 + n) * 128 + idx] = wqv;
  rbuf[t] = wqv; __syncthreads();
  for (int st = 64; st > 0; st >>= 1) { if ((t & 127) < st) rbuf[t] += rbuf[t + st]; __syncthreads(); }
  if (t == 0)   Swqws[n]       = rbuf[0];
  if (t == 128) Swqws[256 + n] = rbuf[128];
  __syncthreads();
  rbuf[t] = bqv; __syncthreads();
  for (int st = 64; st > 0; st >>= 1) { if ((t & 127) < st) rbuf[t] += rbuf[t + st]; __syncthreads(); }
  if (t == 0)   bqws[n]       = rbuf[0];
  if (t == 128) bqws[256 + n] = rbuf[128];
}

// ---------------- K4: sw partials via moment-expanded LN dot ----------------
__global__ __launch_bounds__(256) void k_sw2(
    const u16* __restrict__ kproj, const float* __restrict__ wqws,
    const float* __restrict__ Swqws, const float* __restrict__ bqws,
    float* __restrict__ swpart) {
  const int s = blockIdx.x, g = blockIdx.y;
  const int t = threadIdx.x, w = t >> 6, l = t & 63;
  const int h = l >> 5, j = l & 31;
  __shared__ float part[2][4];
  float accv = 0.f;
  #pragma unroll
  for (int i = 0; i < 4; ++i) {
    const int n = g * 16 + w * 4 + i;
    const u16* kr = kproj + ((size_t)s * 256 + n) * 256 + h * 128 + j * 4;
    const ushort4 k4 = *(const ushort4*)kr;
    const float4 wq4 = *(const float4*)(wqws + ((size_t)h * 256 + n) * 128 + j * 4);
    const float k0 = bf2f(k4.x), k1 = bf2f(k4.y), k2 = bf2f(k4.z), k3 = bf2f(k4.w);
    float sk  = k0 + k1 + k2 + k3;
    float sk2 = k0*k0 + k1*k1 + k2*k2 + k3*k3;
    float skw = k0*wq4.x + k1*wq4.y + k2*wq4.z + k3*wq4.w;
    #pragma unroll
    for (int m = 1; m < 32; m <<= 1) {
      sk  += __shfl_xor(sk,  m, 64);
      sk2 += __shfl_xor(sk2, m, 64);
      skw += __shfl_xor(skw, m, 64);
    }
    const float mu = sk * (1.0f / 128.0f);
    const float var = sk2 * (1.0f / 128.0f) - mu * mu;
    const float rstd = rsqrtf(var + 1e-5f);
    accv += rstd * (skw - mu * Swqws[h * 256 + n]) + bqws[h * 256 + n];
  }
  if (j == 0) part[h][w] = accv;
  __syncthreads();
  if (t < 2) {
    const float r = part[t][0] + part[t][1] + part[t][2] + part[t][3];
    swpart[((size_t)t * 256 + s) * 16 + g] = r;
  }
}

// ---------------- K5: lambda + partial-reduce + softmax -> seq_weights (out) + sqrt scale ----------------
__global__ __launch_bounds__(256) void k_softmax(
    const float* __restrict__ swpart, const float* __restrict__ lq1,
    const float* __restrict__ lk1, const float* __restrict__ lq2,
    const float* __restrict__ lk2, float* __restrict__ seqw_out,
    float* __restrict__ scl) {
  __shared__ float rbuf[256];
  const int t = threadIdx.x;
  const float p1 = (t < 128) ? lq1[t] * lk1[t] : 0.f;
  const float p2 = (t < 128) ? lq2[t] * lk2[t] : 0.f;
  rbuf[t] = p1; __syncthreads();
  for (int st = 128; st > 0; st >>= 1) { if (t < st) rbuf[t] += rbuf[t+st]; __syncthreads(); }
  const float s1 = rbuf[0]; __syncthreads();
  rbuf[t] = p2; __syncthreads();
  for (int st = 128; st > 0; st >>= 1) { if (t < st) rbuf[t] += rbuf[t+st]; __syncthreads(); }
  const float s2 = rbuf[0]; __syncthreads();
  const float lam = expf(s1) - expf(s2) + 0.2f;
  const float sc = (1.0f / sqrtf(128.0f)) / (256.0f + 1e-8f);
  float sw0 = 0.f, sw1 = 0.f;
  {
    const float* p0 = swpart + (size_t)t * 16;
    const float* p1p = swpart + (size_t)(256 + t) * 16;
    #pragma unroll
    for (int kk = 0; kk < 4; ++kk) {
      const float4 a = *(const float4*)(p0 + kk * 4);
      const float4 b = *(const float4*)(p1p + kk * 4);
      sw0 += a.x + a.y + a.z + a.w;
      sw1 += b.x + b.y + b.z + b.w;
    }
    sw0 *= sc; sw1 *= sc;
  }
  const float swv = sw0 - lam * sw1;
  rbuf[t] = swv; __syncthreads();
  for (int st = 128; st > 0; st >>= 1) { if (t < st) rbuf[t] = fmaxf(rbuf[t], rbuf[t+st]); __syncthreads(); }
  const float mx = rbuf[0]; __syncthreads();
  const float e = expf(swv - mx);
  rbuf[t] = e; __syncthreads();
  for (int st = 128; st > 0; st >>= 1) { if (t < st) rbuf[t] += rbuf[t+st]; __syncthreads(); }
  const float Z = rbuf[0];
  const float wgt = e / Z;
  seqw_out[t] = wgt;
  scl[t] = sqrtf(wgt + 1e-8f);
}

// ---------------- K6: transpose+scale -> AscT/BscT bf16 [8192 rows ic][256 s] ----------------
__global__ __launch_bounds__(256) void k_scaleT(
    const float* __restrict__ araw, const float* __restrict__ braw,
    const float* __restrict__ scl, u16* __restrict__ AscT, u16* __restrict__ BscT) {
  __shared__ float tileT[32][257];
  const int t = threadIdx.x;
  const int n = blockIdx.x;
  for (int pass = 0; pass < 2; ++pass) {
    const float* src = pass ? braw : araw;
    u16* dst = pass ? BscT : AscT;
    if (pass) __syncthreads();
    {
      const int sl = t >> 5, c = t & 31;
      for (int it = 0; it < 32; ++it) {
        const int s = it * 8 + sl;
        tileT[c][s] = src[((size_t)s * 256 + n) * 32 + c] * scl[s];
      }
    }
    __syncthreads();
    {
      const int c = t >> 3, s0 = (t & 7) * 32;
      u16* drow = dst + (size_t)(n * 32 + c) * 256 + s0;
      #pragma unroll
      for (int kk = 0; kk < 4; ++kk) {
        ushort4 p0, p1;
        p0.x = f2bf(tileT[c][s0 + kk*8 + 0]); p0.y = f2bf(tileT[c][s0 + kk*8 + 1]);
        p0.z = f2bf(tileT[c][s0 + kk*8 + 2]); p0.w = f2bf(tileT[c][s0 + kk*8 + 3]);
        p1.x = f2bf(tileT[c][s0 + kk*8 + 4]); p1.y = f2bf(tileT[c][s0 + kk*8 + 5]);
        p1.z = f2bf(tileT[c][s0 + kk*8 + 6]); p1.w = f2bf(tileT[c][s0 + kk*8 + 7]);
        *(ushort4*)(drow + kk*8 + 0) = p0;
        *(ushort4*)(drow + kk*8 + 4) = p1;
      }
    }
  }
}

// ---------------- K6b: wp f32 -> bf16 ----------------
__global__ __launch_bounds__(256) void k_wpack(const float* __restrict__ wp, u16* __restrict__ wpbf) {
  const size_t i = ((size_t)blockIdx.x * 256 + threadIdx.x) * 4;
  const float4 v = *(const float4*)&wp[i];
  ushort4 o; o.x = f2bf(v.x); o.y = f2bf(v.y); o.z = f2bf(v.z); o.w = f2bf(v.w);
  *(ushort4*)&wpbf[i] = o;
}

// ---------------- K7: FUSED outer+pair+SiLU (v2: 64KB LDS, barrier-free phase 2) ----------------
// block: ic-tile 128 x je-tile 256. grid (64, 32). dynamic LDS 64KB.
// phase 1: outer GEMM 128x256 K=256; As/Bs stage @0 (24KB, aliases P region, dead at repack)
// repack:  acc -> P[32 ij][1024 ce] bf16 @0 (64KB), XOR swizzle (ij&7)<<4
// phase 2: pair M=32 x N=256 K=1024; A from P (LDS), B direct global->VGPR (wp L2-hot),
//          NO barriers, NO LDS staging -> compiler pipelines loads.
__global__ __launch_bounds__(256, 2) void k_op(
    const u16* __restrict__ AscT, const u16* __restrict__ BscT,
    const u16* __restrict__ wpbf, const float* __restrict__ bp,
    float* __restrict__ out) {
  extern __shared__ char lds_dyn[];
  char* Pb = lds_dyn;                        // P[32][1024] bf16, row stride 2048B (after phase 1)
  const int t = threadIdx.x, l = t & 63, wid = t >> 6;
  const int wm = wid >> 1, wn = wid & 1;
  const int ib = blockIdx.x, jb = blockIdx.y;
  const int lrow = l >> 2, lslot = l & 3;
  const int ksl = ((l >> 4) ^ ((l >> 1) & 3)) * 8;

  // ---- phase 1: outer tile 128 ic x 256 je, K=256 ----
  u16* As = (u16*)lds_dyn;           // 128x32 = 4096 u16 (8KB)
  u16* Bs = (u16*)lds_dyn + 4096;    // 256x32 = 8192 u16 (16KB)
  f32x4 acc[4][8] = {};
  for (int kb = 0; kb < 256; kb += 32) {
    #pragma unroll
    for (int q = 0; q < 2; ++q) {
      const int op = wid * 2 + q;
      const int row = op * 16 + lrow;
      gload16(AscT + (size_t)(ib * 128 + row) * 256 + kb + ((lslot ^ ((row >> 1) & 3)) * 8),
              As + op * 512);
    }
    #pragma unroll
    for (int q = 0; q < 4; ++q) {
      const int op = wid * 4 + q;
      const int row = op * 16 + lrow;
      gload16(BscT + (size_t)(jb * 256 + row) * 256 + kb + ((lslot ^ ((row >> 1) & 3)) * 8),
              Bs + op * 512);
    }
    __syncthreads();
    bf16x8 af[4], bfr[8];
    #pragma unroll
    for (int mt = 0; mt < 4; ++mt)
      af[mt] = *(const bf16x8*)&As[(wm * 64 + mt * 16 + (l & 15)) * 32 + ksl];
    #pragma unroll
    for (int nt = 0; nt < 8; ++nt)
      bfr[nt] = *(const bf16x8*)&Bs[(wn * 128 + nt * 16 + (l & 15)) * 32 + ksl];
    #pragma unroll
    for (int mt = 0; mt < 4; ++mt)
      #pragma unroll
      for (int nt = 0; nt < 8; ++nt)
        acc[mt][nt] = __builtin_amdgcn_mfma_f32_16x16x32_bf16(af[mt], bfr[nt], acc[mt][nt], 0, 0, 0);
    __syncthreads();
  }

  // ---- repack: acc -> P[ij][ce] bf16, swizzled (As/Bs dead, safe to overwrite) ----
  {
    #pragma unroll
    for (int mt = 0; mt < 4; ++mt) {
      #pragma unroll
      for (int nt = 0; nt < 8; ++nt) {
        const int ij = (wm * 2 + (mt >> 1)) * 8 + wn * 4 + (nt >> 1);
        const int e  = (nt & 1) * 16 + (l & 15);
        #pragma unroll
        for (int r = 0; r < 4; ++r) {
          const int c = (mt & 1) * 16 + (l >> 4) * 4 + r;
          const int ce = c * 32 + e;
          *(u16*)(Pb + ij * 2048 + ((ce * 2) ^ ((ij & 7) << 4))) = f2bf(acc[mt][nt][r]);
        }
      }
    }
  }
  __syncthreads();   // P complete

  // ---- phase 2: pair = P @ wp^T, M=32, N=256, K=1024. No barriers. ----
  f32x4 pacc[2][4] = {};
  const int koff = (l >> 4) * 8;
  for (int s = 0; s < 32; ++s) {
    const int kb = s * 32;
    bf16x8 paf[2], bfr[4];
    #pragma unroll
    for (int nt = 0; nt < 4; ++nt) {
      const int p_col = wid * 64 + nt * 16 + (l & 15);
      bfr[nt] = *(const bf16x8*)(wpbf + (size_t)p_col * 1024 + kb + koff);
    }
    #pragma unroll
    for (int mf = 0; mf < 2; ++mf) {
      const int row = mf * 16 + (l & 15);
      paf[mf] = *(const bf16x8*)(Pb + row * 2048 + (((kb + koff) * 2) ^ ((row & 7) << 4)));
    }
    #pragma unroll
    for (int mf = 0; mf < 2; ++mf)
      #pragma unroll
      for (int nt = 0; nt < 4; ++nt)
        pacc[mf][nt] = __builtin_amdgcn_mfma_f32_16x16x32_bf16(paf[mf], bfr[nt], pacc[mf][nt], 0, 0, 0);
  }
  __syncthreads();   // all P reads done before overwriting with pairS

  // ---- epilogue: bias, SiLU, store ----
  float* pairS = (float*)Pb;     // [32][260] f32 = 33280 B <= 64KB
  {
    float bpv[4];
    #pragma unroll
    for (int nt = 0; nt < 4; ++nt) bpv[nt] = bp[wid * 64 + nt * 16 + (l & 15)];
    #pragma unroll
    for (int mf = 0; mf < 2; ++mf)
      #pragma unroll
      for (int nt = 0; nt < 4; ++nt) {
        const int col = wid * 64 + nt * 16 + (l & 15);
        #pragma unroll
        for (int r = 0; r < 4; ++r) {
          const int row = mf * 16 + (l >> 4) * 4 + r;
          pairS[row * 260 + col] = pacc[mf][nt][r] + bpv[nt];
        }
      }
  }
  __syncthreads();
  {
    const int r32 = t >> 3, h0 = (t & 7) * 16;
    const int i_loc = r32 >> 3, j_loc = r32 & 7;
    float* orow = out + ((size_t)(ib * 4 + i_loc) * 256 + jb * 8 + j_loc) * 128 + h0;
    #pragma unroll
    for (int kk = 0; kk < 4; ++kk) {
      const float4 xh = *(const float4*)&pairS[r32 * 260 + h0 + kk * 4];
      const float4 g  = *(const float4*)&pairS[r32 * 260 + 128 + h0 + kk * 4];
      float4 o;
      o.x = xh.x * g.x / (1.f + __expf(-g.x));
      o.y = xh.y * g.y / (1.f + __expf(-g.y));
      o.z = xh.z * g.z / (1.f + __expf(-g.z));
      o.w = xh.w * g.w / (1.f + __expf(-g.w));
      *(float4*)&orow[kk * 4] = o;
    }
  }
}

extern "C" void kernel_launch(void* const* d_in, const int* in_sizes, int n_in,
                              void* d_out, int out_size, void* d_ws, size_t ws_size,
                              hipStream_t stream) {
  const float* msa = (const float*)d_in[0];
  const float* lnw = (const float*)d_in[4];
  const float* lnb = (const float*)d_in[5];
  const float* qw  = (const float*)d_in[6];
  const float* qnw = (const float*)d_in[7];
  const float* qnb = (const float*)d_in[8];
  const float* knw = (const float*)d_in[9];
  const float* knb = (const float*)d_in[10];
  const float* lq1 = (const float*)d_in[11];
  const float* lk1 = (const float*)d_in[12];
  const float* lq2 = (const float*)d_in[13];
  const float* lk2 = (const float*)d_in[14];
  const float* wl  = (const float*)d_in[15];
  const float* wr  = (const float*)d_in[16];
  const float* wp  = (const float*)d_in[17];
  const float* bp  = (const float*)d_in[18];
  const float* kw  = (const float*)d_in[19];
  float* out = (float*)d_out;

  char* ws = (char*)d_ws;
  u16*   AscT  = (u16*)(ws);                    //  0 .. 4 MB
  u16*   BscT  = (u16*)(ws + 4194304);          //  4 .. 8 MB
  u16*   wpbf  = (u16*)(ws + 8388608);          //  8 .. 8.5 MB
  float* sclws = (float*)(ws + 9177088);
  u16*   Wbf   = (u16*)(ws + 9178112);          // 320x256 bf16
  u16*   xbf   = (u16*)(ws + 9437184);          //  9 .. 42.5 MB
  u16*   kproj = (u16*)(ws + 42991616);         // 42.5 .. 76.5 MB
  float* araw  = (float*)(ws + 76546048);       // 76.5 .. 84.9 MB
  float* braw  = (float*)(ws + 84934656);       // 84.9 .. 93.3 MB
  float* wqws  = (float*)(ws + 93323264);       // [2][256][128] f32
  float* swpart= (float*)(ws + 93585408);       // [2][256][16] f32
  float* Swqws = (float*)(ws + 93618176);
  float* bqws  = (float*)(ws + 93620224);

  k_ln<<<16384, 256, 0, stream>>>(msa, lnw, lnb, xbf);
  k_wpackW<<<320, 256, 0, stream>>>(kw, wl, wr, Wbf);
  k_proj_mfma<<<dim3(512, 5), 256, 0, stream>>>(xbf, Wbf, kproj, araw, braw);
  k_q<<<256, 256, 0, stream>>>(xbf, qw, qnw, qnb, knw, knb, wqws, Swqws, bqws);
  k_sw2<<<dim3(256, 16), 256, 0, stream>>>(kproj, wqws, Swqws, bqws, swpart);
  k_softmax<<<1, 256, 0, stream>>>(swpart, lq1, lk1, lq2, lk2, out + 8388608, sclws);
  k_scaleT<<<256, 256, 0, stream>>>(araw, braw, sclws, AscT, BscT);
  k_wpack<<<256, 256, 0, stream>>>(wp, wpbf);
  k_op<<<dim3(64, 32), 256, 65536, stream>>>(AscT, BscT, wpbf, bp, out);
}